// Round 18
// baseline (873.125 us; speedup 1.0000x reference)
//
#include <hip/hip_runtime.h>
#include <hip/hip_bf16.h>
#include <stdint.h>

#define NROWS 12288
#define DIM   512
#define KNBR  10

#define NC    8            // column chunks
#define CHUNK (NROWS / NC) // 1536
#define BT    64           // tile rows
#define BNT   128          // tile cols
#define CT    (CHUNK / BNT)// 12 col-tiles per block
#define NRB   (NROWS / BT) // 192 row blocks
#define PHK   64           // K per barrier phase
#define NPH   (DIM / PHK)  // 8 phases

// exp(-x) == +0.0f (round-nearest) for all x >= 104 (exp(-104) < 2^-150).
#define UNDERFLOW_DIST 104.0f

typedef __attribute__((ext_vector_type(8))) short s16x8;
typedef __attribute__((ext_vector_type(4))) float f32x4;
typedef unsigned int u32;

static __device__ __forceinline__ unsigned short f2bf(float x) {
  __hip_bfloat16 b = __float2bfloat16(x);
  return *reinterpret_cast<unsigned short*>(&b);
}

static __device__ __forceinline__ void gload16(const void* g, void* l) {
  __builtin_amdgcn_global_load_lds(
      (const __attribute__((address_space(1))) u32*)g,
      (__attribute__((address_space(3))) u32*)l, 16, 0, 0);
}

// Stable top-k insert: keeps list sorted by (value desc, index asc).
#define TOPK_INSERT(TV, TI, V, IDX)                                              \
  do {                                                                           \
    float _v = (V); int _i = (IDX);                                              \
    if (_v > TV[9] || (_v == TV[9] && _i < TI[9])) {                             \
      TV[9] = _v; TI[9] = _i;                                                    \
      _Pragma("unroll")                                                          \
      for (int _s = 9; _s > 0; --_s) {                                           \
        bool _sw = (TV[_s] > TV[_s-1]) ||                                        \
                   (TV[_s] == TV[_s-1] && TI[_s] < TI[_s-1]);                    \
        if (_sw) {                                                               \
          float _tf = TV[_s]; TV[_s] = TV[_s-1]; TV[_s-1] = _tf;                 \
          int   _ti = TI[_s]; TI[_s] = TI[_s-1]; TI[_s-1] = _ti;                 \
        }                                                                        \
      }                                                                          \
    }                                                                            \
  } while (0)

// ---------------- Kernel 1: norms + bf16 conversion ----------------
__global__ __launch_bounds__(256) void prep_kernel(
    const float* __restrict__ f, float* __restrict__ sq,
    unsigned short* __restrict__ fbf) {
  const int wid = threadIdx.x >> 6;
  const int lane = threadIdx.x & 63;
  const int row = blockIdx.x * 4 + wid;
  const float4* fr = (const float4*)(f + (size_t)row * DIM);
  ushort4* br = (ushort4*)(fbf + (size_t)row * DIM);
  float s = 0.f;
#pragma unroll
  for (int u = 0; u < 2; ++u) {
    float4 v = fr[u * 64 + lane];
    s += v.x * v.x + v.y * v.y + v.z * v.z + v.w * v.w;
    ushort4 h;
    h.x = f2bf(v.x); h.y = f2bf(v.y); h.z = f2bf(v.z); h.w = f2bf(v.w);
    br[u * 64 + lane] = h;
  }
#pragma unroll
  for (int off = 32; off; off >>= 1) s += __shfl_down(s, off);
  if (lane == 0) sq[row] = s;
}

// ---------------- Kernel 2: 64x128 tile, K=64 phases (2x work/barrier) ------
// grid (192, 8) -- r15's verified 2D grid. Change vs r15 (487 us): each
// barrier phase now covers K=64 (two K=32 halves processed sequentially, so
// the per-half register live set is IDENTICAL to r15 -- no acc growth), i.e.
// 12 ds_read + 16 MFMA per wave per phase and 96 phases/block instead of 192.
// The ladder consistently rewards more work per barrier-phase (r9->r10 +7%,
// r14->r15 +18%); per-phase sync/turnaround cost is the residual bound.
// 2 phase-buffers (A 8KB, B 16KB each; 48KB): stage(ph+1) at phase top into
// the buffer phase ph-1 used (reads completed before barrier(ph-1) -> WAR
// safe); vmcnt(0) at phase end == "phase ph+1 staged". 128B-row layout and
// XOR swizzle are r13's verified formulas (slot^(row&7) / ((h*4+kg)^(fr&7))).
__global__ __launch_bounds__(256) void gram_topk(
    const unsigned short* __restrict__ fbf, const float* __restrict__ sq,
    float2* __restrict__ part, float* __restrict__ out) {
  // smem: A0 @0 (8KB) | A1 @8192 | B0 @16384 (16KB) | B1 @32768 = 48KB.
  // simf [64][130] f32 (33280B) and the merge dump (20480B) overlay the
  // buffers (dead at those points).
  __shared__ __align__(16) char smem[49152];
  __shared__ float sqrow[BT];
  __shared__ float sqcs[BNT];
  float* simf = (float*)smem;

  const int t = threadIdx.x;
  const int lane = t & 63, wid = t >> 6;
  const int wr = wid >> 1, wc = wid & 1;      // wave -> 32-row half, 64-col half
  const int fr = lane & 15, kg = lane >> 4;   // MFMA fragment coords
  const int brow = blockIdx.x * BT;
  const int chunk = blockIdx.y;

  // Zero-fill this block's 1/1536 slice of the output.
  {
    const int bid = blockIdx.y * NRB + blockIdx.x;         // 0..1535
    const int per = NROWS * NROWS / (NRB * NC) / 4;        // f32x4 per block
    f32x4* o4 = (f32x4*)out + (size_t)bid * per;
    f32x4 z = {0.f, 0.f, 0.f, 0.f};
    for (int i = t; i < per; i += 256) o4[i] = z;
  }
  if (t < BT) sqrow[t] = sq[brow + t];

  float tv[10]; int ti[10];
#pragma unroll
  for (int s = 0; s < 10; ++s) { tv[s] = -INFINITY; ti[s] = 0x7fffffff; }

  // staging: rows are 128B (8 x 16B slots); chunk (row,slot) holds source
  // k-group slot^(row&7) (r13-verified). Thread t covers rows t>>3 (+32 per
  // extra gload -- 32 == 0 mod 8 keeps the XOR term constant across calls).
  const int srow0 = t >> 3;
  const size_t gA = (size_t)srow0 * DIM + (((t & 7) ^ (srow0 & 7)) * 8);
  const int dB = wid * 1024;   // wave-uniform LDS base (+lane*16 by HW)
  const unsigned short* arow = fbf + (size_t)brow * DIM;

  for (int ct = 0; ct < CT; ++ct) {
    const int bcol = chunk * CHUNK + ct * BNT;
    const unsigned short* bp = fbf + (size_t)bcol * DIM;
    if (t < BNT) sqcs[t] = sq[bcol + t];  // older than STAGE; drained below

    f32x4 acc[2][4];
#pragma unroll
    for (int m = 0; m < 2; ++m)
#pragma unroll
      for (int n = 0; n < 4; ++n)
#pragma unroll
        for (int q = 0; q < 4; ++q) acc[m][n][q] = 0.f;

    // STAGE one K=64 phase-slice: A 2 gloads (64 rows x 128B), B 4 gloads
#define STAGE(KT, BUF)                                                       \
    do {                                                                     \
      char* ab_ = smem + (BUF) * 8192;                                       \
      char* bb_ = smem + 16384 + (BUF) * 16384;                              \
      gload16(arow + (KT) + gA, ab_ + dB);                                   \
      gload16(arow + (KT) + gA + 32 * DIM, ab_ + 4096 + dB);                 \
      gload16(bp + (KT) + gA, bb_ + dB);                                     \
      gload16(bp + (KT) + gA + 32 * DIM, bb_ + 4096 + dB);                   \
      gload16(bp + (KT) + gA + 64 * DIM, bb_ + 8192 + dB);                   \
      gload16(bp + (KT) + gA + 96 * DIM, bb_ + 12288 + dB);                  \
    } while (0)

    STAGE(0, 0);
    asm volatile("s_waitcnt vmcnt(0)" ::: "memory");  // phase 0 + sqcs landed
    __builtin_amdgcn_s_barrier();
    __builtin_amdgcn_sched_barrier(0);

#pragma unroll
    for (int ph = 0; ph < NPH; ++ph) {
      // stage next phase into the buffer phase ph-1 used (WAR-safe).
      if (ph < NPH - 1) STAGE((ph + 1) * PHK, (ph + 1) & 1);
      const char* ab = smem + (ph & 1) * 8192;
      const char* bb = smem + 16384 + (ph & 1) * 16384;
#pragma unroll
      for (int h = 0; h < 2; ++h) {
        const int ob = (((h << 2) | kg) ^ (fr & 7)) << 4;
        s16x8 a0 = *(const s16x8*)(ab + (wr * 32 + fr) * 128 + ob);
        s16x8 a1 = *(const s16x8*)(ab + (wr * 32 + 16 + fr) * 128 + ob);
        s16x8 b[4];
#pragma unroll
        for (int n = 0; n < 4; ++n)
          b[n] = *(const s16x8*)(bb + (wc * 64 + n * 16 + fr) * 128 + ob);
#pragma unroll
        for (int n = 0; n < 4; ++n) {
          acc[0][n] = __builtin_amdgcn_mfma_f32_16x16x32_bf16(a0, b[n], acc[0][n], 0, 0, 0);
          acc[1][n] = __builtin_amdgcn_mfma_f32_16x16x32_bf16(a1, b[n], acc[1][n], 0, 0, 0);
        }
      }
      asm volatile("s_waitcnt vmcnt(0)" ::: "memory");  // next phase landed
      __builtin_amdgcn_s_barrier();
      __builtin_amdgcn_sched_barrier(0);
    }
#undef STAGE

    // Per-thread column norms (4 distinct cols), register-hoisted.
    float sqcn[4];
#pragma unroll
    for (int n = 0; n < 4; ++n) sqcn[n] = sqcs[wc * 64 + n * 16 + fr];

    // Underflow vote: any dist < 104 in this 64x128 tile?
    bool under = (ct > 0);
#pragma unroll
    for (int m = 0; m < 2; ++m)
#pragma unroll
      for (int n = 0; n < 4; ++n)
#pragma unroll
        for (int q = 0; q < 4; ++q) {
          const int rl = wr * 32 + m * 16 + kg * 4 + q;
          const float dist = sqrow[rl] + sqcn[n] - 2.0f * acc[m][n][q];
          under = under && (dist >= UNDERFLOW_DIST);
        }
    const int skip = __syncthreads_and((int)under);  // block-uniform

    if (!skip) {
      // Full epilogue (rare): dist -> sim, LDS tile (overlays buffers), scan.
#pragma unroll
      for (int m = 0; m < 2; ++m)
#pragma unroll
        for (int n = 0; n < 4; ++n)
#pragma unroll
          for (int q = 0; q < 4; ++q) {
            int rl = wr * 32 + m * 16 + kg * 4 + q;
            int cl = wc * 64 + n * 16 + fr;
            float dist = sqrow[rl] + sqcn[n] - 2.0f * acc[m][n][q];
            float sv = ((brow + rl) == (bcol + cl)) ? 0.0f
                       : __expf(-fmaxf(dist, 0.0f));
            simf[rl * 130 + cl] = sv;
          }
      __syncthreads();
      {
        const int c0 = wid * 32;   // wave wid scans its 32-col sub-slice
#pragma unroll
        for (int c = 0; c < 32; ++c) {
          float v = simf[lane * 130 + c0 + c];
          TOPK_INSERT(tv, ti, v, bcol + c0 + c);
        }
      }
      __syncthreads();   // scan done before buffers are re-staged next ct
    }
  }

  // Dump 4 partial lists per row, merge (thread t<64 owns row brow+t),
  // write the row's chunk top-10 to the workspace.
#pragma unroll
  for (int s = 0; s < 10; ++s) {
    simf[(lane * 4 + wid) * 20 + s * 2]     = tv[s];
    simf[(lane * 4 + wid) * 20 + s * 2 + 1] = __int_as_float(ti[s]);
  }
  __syncthreads();
  if (t < BT) {
    float mv[10]; int mi[10];
#pragma unroll
    for (int s = 0; s < 10; ++s) { mv[s] = -INFINITY; mi[s] = 0x7fffffff; }
#pragma unroll
    for (int p = 0; p < 4; ++p)
#pragma unroll
      for (int s = 0; s < 10; ++s) {
        float v = simf[(t * 4 + p) * 20 + s * 2];
        int idx = __float_as_int(simf[(t * 4 + p) * 20 + s * 2 + 1]);
        TOPK_INSERT(mv, mi, v, idx);
      }
    float2* dst = part + ((size_t)(brow + t) * NC + chunk) * 10;
#pragma unroll
    for (int s = 0; s < 10; ++s) dst[s] = make_float2(mv[s], __int_as_float(mi[s]));
  }
}

// ---------------- Kernel 3: merge NC chunk lists per row, scatter ones ------
__global__ __launch_bounds__(256) void merge_scatter(
    const float2* __restrict__ part, float* __restrict__ out) {
  const int t = threadIdx.x;
  if (t >= 128) return;
  const int r = blockIdx.x * 128 + t;
  float mv[10]; int mi[10];
#pragma unroll
  for (int s = 0; s < 10; ++s) { mv[s] = -INFINITY; mi[s] = 0x7fffffff; }
  const float2* p = part + (size_t)r * NC * 10;
#pragma unroll
  for (int c = 0; c < NC * 10; ++c)
    TOPK_INSERT(mv, mi, p[c].x, __float_as_int(p[c].y));
  float* orow = out + (size_t)r * NROWS;
#pragma unroll
  for (int s = 0; s < 10; ++s) orow[mi[s]] = 1.0f;
}

// ---------------- Fallback (round-1 single-kernel path, 12.6 MB ws) ---------
__global__ __launch_bounds__(256) void knn_fallback(
    const unsigned short* __restrict__ fbf, const float* __restrict__ sq,
    float* __restrict__ out) {
  __shared__ short aT[64][32];
  __shared__ short bT[64][32];
  __shared__ float simf[5120];
  __shared__ float sqrow[64];

  const int t = threadIdx.x;
  const int lane = t & 63, wid = t >> 6;
  const int wr = wid >> 1, wc = wid & 1;
  const int fr = lane & 15, kg = lane >> 4;
  const int brow = blockIdx.x * 64;

  {
    f32x4* o4 = (f32x4*)(out + (size_t)brow * NROWS);
    const int total4 = 64 * NROWS / 4;
    f32x4 z = {0.f, 0.f, 0.f, 0.f};
    for (int i = t; i < total4; i += 256) o4[i] = z;
  }
  if (t < 64) sqrow[t] = sq[brow + t];

  float tv[10]; int ti[10];
#pragma unroll
  for (int s = 0; s < 10; ++s) { tv[s] = -INFINITY; ti[s] = 0x7fffffff; }
  const int sstage_r = t >> 2;
  const int sstage_k = (t & 3) * 8;

  for (int ctile = 0; ctile < NROWS / 64; ++ctile) {
    const int bcol = ctile * 64;
    f32x4 acc[2][2];
#pragma unroll
    for (int m = 0; m < 2; ++m)
#pragma unroll
      for (int n = 0; n < 2; ++n)
#pragma unroll
        for (int q = 0; q < 4; ++q) acc[m][n][q] = 0.f;

    for (int kt = 0; kt < DIM; kt += 32) {
      *(s16x8*)&aT[sstage_r][sstage_k] =
          *(const s16x8*)&fbf[(size_t)(brow + sstage_r) * DIM + kt + sstage_k];
      *(s16x8*)&bT[sstage_r][sstage_k] =
          *(const s16x8*)&fbf[(size_t)(bcol + sstage_r) * DIM + kt + sstage_k];
      __syncthreads();
      s16x8 a0 = *(const s16x8*)&aT[wr * 32 + fr][kg * 8];
      s16x8 a1 = *(const s16x8*)&aT[wr * 32 + 16 + fr][kg * 8];
      s16x8 b0 = *(const s16x8*)&bT[wc * 32 + fr][kg * 8];
      s16x8 b1 = *(const s16x8*)&bT[wc * 32 + 16 + fr][kg * 8];
      acc[0][0] = __builtin_amdgcn_mfma_f32_16x16x32_bf16(a0, b0, acc[0][0], 0, 0, 0);
      acc[0][1] = __builtin_amdgcn_mfma_f32_16x16x32_bf16(a0, b1, acc[0][1], 0, 0, 0);
      acc[1][0] = __builtin_amdgcn_mfma_f32_16x16x32_bf16(a1, b0, acc[1][0], 0, 0, 0);
      acc[1][1] = __builtin_amdgcn_mfma_f32_16x16x32_bf16(a1, b1, acc[1][1], 0, 0, 0);
      __syncthreads();
    }
#pragma unroll
    for (int m = 0; m < 2; ++m)
#pragma unroll
      for (int n = 0; n < 2; ++n)
#pragma unroll
        for (int q = 0; q < 4; ++q) {
          int rl = wr * 32 + m * 16 + kg * 4 + q;
          int cl = wc * 32 + n * 16 + fr;
          float dist = sqrow[rl] + sq[bcol + cl] - 2.0f * acc[m][n][q];
          float sv = ((brow + rl) == (bcol + cl)) ? 0.0f : __expf(-fmaxf(dist, 0.0f));
          simf[rl * 65 + cl] = sv;
        }
    __syncthreads();
    {
      const int c0 = wid * 16;
#pragma unroll
      for (int c = 0; c < 16; ++c) {
        float v = simf[lane * 65 + c0 + c];
        TOPK_INSERT(tv, ti, v, bcol + c0 + c);
      }
    }
    __syncthreads();
  }
#pragma unroll
  for (int s = 0; s < 10; ++s) {
    simf[(lane * 4 + wid) * 20 + s * 2]     = tv[s];
    simf[(lane * 4 + wid) * 20 + s * 2 + 1] = __int_as_float(ti[s]);
  }
  __syncthreads();
  if (t < 64) {
    float mv[10]; int mi[10];
#pragma unroll
    for (int s = 0; s < 10; ++s) { mv[s] = -INFINITY; mi[s] = 0x7fffffff; }
#pragma unroll
    for (int p = 0; p < 4; ++p)
#pragma unroll
      for (int s = 0; s < 10; ++s) {
        float v = simf[(t * 4 + p) * 20 + s * 2];
        int idx = __float_as_int(simf[(t * 4 + p) * 20 + s * 2 + 1]);
        TOPK_INSERT(mv, mi, v, idx);
      }
    float* orow = out + (size_t)(brow + t) * NROWS;
#pragma unroll
    for (int s = 0; s < 10; ++s) orow[mi[s]] = 1.0f;
  }
}

extern "C" void kernel_launch(void* const* d_in, const int* in_sizes, int n_in,
                              void* d_out, int out_size, void* d_ws, size_t ws_size,
                              hipStream_t stream) {
  const float* f = (const float*)d_in[0];
  float* out = (float*)d_out;

  const size_t sq_bytes   = (size_t)NROWS * sizeof(float);          // 49152
  const size_t fbf_bytes  = (size_t)NROWS * DIM * sizeof(unsigned short);
  const size_t part_bytes = (size_t)NROWS * NC * 10 * sizeof(float2);

  float* sq = (float*)d_ws;
  unsigned short* fbf = (unsigned short*)((char*)d_ws + sq_bytes);
  float2* part = (float2*)((char*)d_ws + sq_bytes + fbf_bytes);

  if (ws_size >= sq_bytes + fbf_bytes + part_bytes) {
    prep_kernel<<<NROWS / 4, 256, 0, stream>>>(f, sq, fbf);
    gram_topk<<<dim3(NRB, NC), 256, 0, stream>>>(fbf, sq, part, out);
    merge_scatter<<<NROWS / 128, 256, 0, stream>>>(part, out);
  } else if (ws_size >= sq_bytes + fbf_bytes) {
    prep_kernel<<<NROWS / 4, 256, 0, stream>>>(f, sq, fbf);
    knn_fallback<<<NROWS / 64, 256, 0, stream>>>(fbf, sq, out);
  }
}

// Round 19
// 507.073 us; speedup vs baseline: 1.7219x; 1.7219x over previous
//
#include <hip/hip_runtime.h>
#include <hip/hip_bf16.h>
#include <stdint.h>

#define NROWS 12288
#define DIM   512
#define KNBR  10

#define NC    8            // column chunks
#define CHUNK (NROWS / NC) // 1536
#define BT    64           // tile rows
#define BNT   128          // tile cols
#define CT    (CHUNK / BNT)// 12 col-tiles per block
#define NRB   (NROWS / BT) // 192 row blocks
#define KS    32           // K per pipeline step
#define KST   (DIM / KS)   // 16 k-steps

// exp(-x) == +0.0f (round-nearest) for all x >= 104 (exp(-104) < 2^-150).
#define UNDERFLOW_DIST 104.0f

typedef __attribute__((ext_vector_type(8))) short s16x8;
typedef __attribute__((ext_vector_type(4))) float f32x4;
typedef unsigned int u32;

static __device__ __forceinline__ unsigned short f2bf(float x) {
  __hip_bfloat16 b = __float2bfloat16(x);
  return *reinterpret_cast<unsigned short*>(&b);
}

static __device__ __forceinline__ void gload16(const void* g, void* l) {
  __builtin_amdgcn_global_load_lds(
      (const __attribute__((address_space(1))) u32*)g,
      (__attribute__((address_space(3))) u32*)l, 16, 0, 0);
}

// Stable top-k insert: keeps list sorted by (value desc, index asc).
#define TOPK_INSERT(TV, TI, V, IDX)                                              \
  do {                                                                           \
    float _v = (V); int _i = (IDX);                                              \
    if (_v > TV[9] || (_v == TV[9] && _i < TI[9])) {                             \
      TV[9] = _v; TI[9] = _i;                                                    \
      _Pragma("unroll")                                                          \
      for (int _s = 9; _s > 0; --_s) {                                           \
        bool _sw = (TV[_s] > TV[_s-1]) ||                                        \
                   (TV[_s] == TV[_s-1] && TI[_s] < TI[_s-1]);                    \
        if (_sw) {                                                               \
          float _tf = TV[_s]; TV[_s] = TV[_s-1]; TV[_s-1] = _tf;                 \
          int   _ti = TI[_s]; TI[_s] = TI[_s-1]; TI[_s-1] = _ti;                 \
        }                                                                        \
      }                                                                          \
    }                                                                            \
  } while (0)

// ---------------- Kernel 1: norms + bf16 conversion ----------------
__global__ __launch_bounds__(256) void prep_kernel(
    const float* __restrict__ f, float* __restrict__ sq,
    unsigned short* __restrict__ fbf) {
  const int wid = threadIdx.x >> 6;
  const int lane = threadIdx.x & 63;
  const int row = blockIdx.x * 4 + wid;
  const float4* fr = (const float4*)(f + (size_t)row * DIM);
  ushort4* br = (ushort4*)(fbf + (size_t)row * DIM);
  float s = 0.f;
#pragma unroll
  for (int u = 0; u < 2; ++u) {
    float4 v = fr[u * 64 + lane];
    s += v.x * v.x + v.y * v.y + v.z * v.z + v.w * v.w;
    ushort4 h;
    h.x = f2bf(v.x); h.y = f2bf(v.y); h.z = f2bf(v.z); h.w = f2bf(v.w);
    br[u * 64 + lane] = h;
  }
#pragma unroll
  for (int off = 32; off; off >>= 1) s += __shfl_down(s, off);
  if (lane == 0) sq[row] = s;
}

// ---------------- Kernel 2: r15 structure (verified 487 us) + T5 setprio ----
// grid (192, 8), 64x128 tile, acc[2][4], 3-slice counted-vmcnt pipeline,
// STAGE(k+2) issued AFTER the MFMAs (r17's stage-at-top regressed: LDS-write
// port contention with fragment ds_reads), vmcnt(3) never 0 in steady state.
// r16's bid%8 XCD mapping regressed (FETCH 2x; dispatch mapping undefined,
// G16); r18's K=64 2-buffer phases regressed (LDS 50KB -> 2 blocks/CU +
// vmcnt(0) serialization). This round: r15 verbatim + s_setprio(1) around the
// MFMA cluster (T5, isolated this time; m224 regime: phase-split schedule).
__global__ __launch_bounds__(256) void gram_topk(
    const unsigned short* __restrict__ fbf, const float* __restrict__ sq,
    float2* __restrict__ part, float* __restrict__ out) {
  // smem: A slices @0,4096,8192 (64x64B each); B slices @12288,20480,28672
  // (128x64B each) = 36KB. simf [64][130] f32 (33280B) and the merge dump
  // (20480B) overlay the slices (dead at those points).
  __shared__ __align__(16) char smem[36864];
  __shared__ float sqrow[BT];
  __shared__ float sqcs[BNT];
  float* simf = (float*)smem;

  const int t = threadIdx.x;
  const int lane = t & 63, wid = t >> 6;
  const int wr = wid >> 1, wc = wid & 1;      // wave -> 32-row half, 64-col half
  const int fr = lane & 15, kg = lane >> 4;   // MFMA fragment coords
  const int brow = blockIdx.x * BT;
  const int chunk = blockIdx.y;

  // Zero-fill this block's 1/1536 slice of the output.
  {
    const int bid = blockIdx.y * NRB + blockIdx.x;         // 0..1535
    const int per = NROWS * NROWS / (NRB * NC) / 4;        // f32x4 per block
    f32x4* o4 = (f32x4*)out + (size_t)bid * per;
    f32x4 z = {0.f, 0.f, 0.f, 0.f};
    for (int i = t; i < per; i += 256) o4[i] = z;
  }
  if (t < BT) sqrow[t] = sq[brow + t];

  float tv[10]; int ti[10];
#pragma unroll
  for (int s = 0; s < 10; ++s) { tv[s] = -INFINITY; ti[s] = 0x7fffffff; }

  // staging: rows are 64B (4 x 16B slots); chunk c: row=c>>2, slot=c&3, holds
  // source k-group slot^((row>>1)&3). A slice = 256 chunks (1 gload/thread),
  // B slice = 512 chunks (2 gloads/thread; rows +64 keep the same XOR term).
  const int srow0 = t >> 2;
  const size_t gOff = (size_t)srow0 * DIM + (((t & 3) ^ ((srow0 >> 1) & 3)) * 8);
  const int dB = wid * 1024;   // wave-uniform LDS base (+lane*16 by HW)
  const unsigned short* arow = fbf + (size_t)brow * DIM;
  // fragment read slot: kgroup kg stored at slot kg^((row>>1)&3); for all
  // fragment rows (wr*32+fr, +16; wc*64+n*16+fr) ((row>>1)&3) == ((fr>>1)&3).
  const int slotx = (kg ^ ((fr >> 1) & 3)) * 16;

  for (int ct = 0; ct < CT; ++ct) {
    const int bcol = chunk * CHUNK + ct * BNT;
    const unsigned short* bp = fbf + (size_t)bcol * DIM;
    if (t < BNT) sqcs[t] = sq[bcol + t];  // oldest vmem op; drained by vmcnt(3)

    f32x4 acc[2][4];
#pragma unroll
    for (int m = 0; m < 2; ++m)
#pragma unroll
      for (int n = 0; n < 4; ++n)
#pragma unroll
        for (int q = 0; q < 4; ++q) acc[m][n][q] = 0.f;

#define STAGE(KT, BUF)                                                       \
    do {                                                                     \
      gload16(arow + (KT) + gOff, smem + (BUF) * 4096 + dB);                 \
      gload16(bp + (KT) + gOff, smem + 12288 + (BUF) * 8192 + dB);           \
      gload16(bp + (KT) + gOff + 64 * DIM,                                   \
              smem + 12288 + (BUF) * 8192 + 4096 + dB);                      \
    } while (0)

    STAGE(0, 0);
    STAGE(KS, 1);
    asm volatile("s_waitcnt vmcnt(3)" ::: "memory");  // slice 0 + sq landed
    __builtin_amdgcn_s_barrier();                      // ... for every wave
    __builtin_amdgcn_sched_barrier(0);

#pragma unroll
    for (int k = 0; k < KST; ++k) {
      const char* ab = smem + (k % 3) * 4096;
      const char* bb = smem + 12288 + (k % 3) * 8192;
      s16x8 a0 = *(const s16x8*)(ab + (wr * 32 + fr) * 64 + slotx);
      s16x8 a1 = *(const s16x8*)(ab + (wr * 32 + 16 + fr) * 64 + slotx);
      s16x8 b[4];
#pragma unroll
      for (int n = 0; n < 4; ++n)
        b[n] = *(const s16x8*)(bb + (wc * 64 + n * 16 + fr) * 64 + slotx);
      __builtin_amdgcn_s_setprio(1);
#pragma unroll
      for (int n = 0; n < 4; ++n) {
        acc[0][n] = __builtin_amdgcn_mfma_f32_16x16x32_bf16(a0, b[n], acc[0][n], 0, 0, 0);
        acc[1][n] = __builtin_amdgcn_mfma_f32_16x16x32_bf16(a1, b[n], acc[1][n], 0, 0, 0);
      }
      __builtin_amdgcn_s_setprio(0);
      if (k < KST - 2) {
        STAGE((k + 2) * KS, (k + 2) % 3);   // overwrites buf((k-1)%3): safe
        asm volatile("s_waitcnt vmcnt(3)" ::: "memory");  // STAGE(k+1) landed
      } else {
        asm volatile("s_waitcnt vmcnt(0)" ::: "memory");  // tail: drain all
      }
      __builtin_amdgcn_s_barrier();
      __builtin_amdgcn_sched_barrier(0);
    }
#undef STAGE

    // Per-thread column norms (4 distinct cols), register-hoisted.
    float sqcn[4];
#pragma unroll
    for (int n = 0; n < 4; ++n) sqcn[n] = sqcs[wc * 64 + n * 16 + fr];

    // Underflow vote: any dist < 104 in this 64x128 tile?
    bool under = (ct > 0);
#pragma unroll
    for (int m = 0; m < 2; ++m)
#pragma unroll
      for (int n = 0; n < 4; ++n)
#pragma unroll
        for (int q = 0; q < 4; ++q) {
          const int rl = wr * 32 + m * 16 + kg * 4 + q;
          const float dist = sqrow[rl] + sqcn[n] - 2.0f * acc[m][n][q];
          under = under && (dist >= UNDERFLOW_DIST);
        }
    const int skip = __syncthreads_and((int)under);  // block-uniform

    if (!skip) {
      // Full epilogue (rare): dist -> sim, LDS tile (overlays slices), scan.
#pragma unroll
      for (int m = 0; m < 2; ++m)
#pragma unroll
        for (int n = 0; n < 4; ++n)
#pragma unroll
          for (int q = 0; q < 4; ++q) {
            int rl = wr * 32 + m * 16 + kg * 4 + q;
            int cl = wc * 64 + n * 16 + fr;
            float dist = sqrow[rl] + sqcn[n] - 2.0f * acc[m][n][q];
            float sv = ((brow + rl) == (bcol + cl)) ? 0.0f
                       : __expf(-fmaxf(dist, 0.0f));
            simf[rl * 130 + cl] = sv;
          }
      __syncthreads();
      {
        const int c0 = wid * 32;   // wave wid scans its 32-col sub-slice
#pragma unroll
        for (int c = 0; c < 32; ++c) {
          float v = simf[lane * 130 + c0 + c];
          TOPK_INSERT(tv, ti, v, bcol + c0 + c);
        }
      }
      __syncthreads();   // scan done before slices are re-staged next ct
    }
  }

  // Dump 4 partial lists per row, merge (thread t<64 owns row brow+t),
  // write the row's chunk top-10 to the workspace.
#pragma unroll
  for (int s = 0; s < 10; ++s) {
    simf[(lane * 4 + wid) * 20 + s * 2]     = tv[s];
    simf[(lane * 4 + wid) * 20 + s * 2 + 1] = __int_as_float(ti[s]);
  }
  __syncthreads();
  if (t < BT) {
    float mv[10]; int mi[10];
#pragma unroll
    for (int s = 0; s < 10; ++s) { mv[s] = -INFINITY; mi[s] = 0x7fffffff; }
#pragma unroll
    for (int p = 0; p < 4; ++p)
#pragma unroll
      for (int s = 0; s < 10; ++s) {
        float v = simf[(t * 4 + p) * 20 + s * 2];
        int idx = __float_as_int(simf[(t * 4 + p) * 20 + s * 2 + 1]);
        TOPK_INSERT(mv, mi, v, idx);
      }
    float2* dst = part + ((size_t)(brow + t) * NC + chunk) * 10;
#pragma unroll
    for (int s = 0; s < 10; ++s) dst[s] = make_float2(mv[s], __int_as_float(mi[s]));
  }
}

// ---------------- Kernel 3: merge NC chunk lists per row, scatter ones ------
__global__ __launch_bounds__(256) void merge_scatter(
    const float2* __restrict__ part, float* __restrict__ out) {
  const int t = threadIdx.x;
  if (t >= 128) return;
  const int r = blockIdx.x * 128 + t;
  float mv[10]; int mi[10];
#pragma unroll
  for (int s = 0; s < 10; ++s) { mv[s] = -INFINITY; mi[s] = 0x7fffffff; }
  const float2* p = part + (size_t)r * NC * 10;
#pragma unroll
  for (int c = 0; c < NC * 10; ++c)
    TOPK_INSERT(mv, mi, p[c].x, __float_as_int(p[c].y));
  float* orow = out + (size_t)r * NROWS;
#pragma unroll
  for (int s = 0; s < 10; ++s) orow[mi[s]] = 1.0f;
}

// ---------------- Fallback (round-1 single-kernel path, 12.6 MB ws) ---------
__global__ __launch_bounds__(256) void knn_fallback(
    const unsigned short* __restrict__ fbf, const float* __restrict__ sq,
    float* __restrict__ out) {
  __shared__ short aT[64][32];
  __shared__ short bT[64][32];
  __shared__ float simf[5120];
  __shared__ float sqrow[64];

  const int t = threadIdx.x;
  const int lane = t & 63, wid = t >> 6;
  const int wr = wid >> 1, wc = wid & 1;
  const int fr = lane & 15, kg = lane >> 4;
  const int brow = blockIdx.x * 64;

  {
    f32x4* o4 = (f32x4*)(out + (size_t)brow * NROWS);
    const int total4 = 64 * NROWS / 4;
    f32x4 z = {0.f, 0.f, 0.f, 0.f};
    for (int i = t; i < total4; i += 256) o4[i] = z;
  }
  if (t < 64) sqrow[t] = sq[brow + t];

  float tv[10]; int ti[10];
#pragma unroll
  for (int s = 0; s < 10; ++s) { tv[s] = -INFINITY; ti[s] = 0x7fffffff; }
  const int sstage_r = t >> 2;
  const int sstage_k = (t & 3) * 8;

  for (int ctile = 0; ctile < NROWS / 64; ++ctile) {
    const int bcol = ctile * 64;
    f32x4 acc[2][2];
#pragma unroll
    for (int m = 0; m < 2; ++m)
#pragma unroll
      for (int n = 0; n < 2; ++n)
#pragma unroll
        for (int q = 0; q < 4; ++q) acc[m][n][q] = 0.f;

    for (int kt = 0; kt < DIM; kt += 32) {
      *(s16x8*)&aT[sstage_r][sstage_k] =
          *(const s16x8*)&fbf[(size_t)(brow + sstage_r) * DIM + kt + sstage_k];
      *(s16x8*)&bT[sstage_r][sstage_k] =
          *(const s16x8*)&fbf[(size_t)(bcol + sstage_r) * DIM + kt + sstage_k];
      __syncthreads();
      s16x8 a0 = *(const s16x8*)&aT[wr * 32 + fr][kg * 8];
      s16x8 a1 = *(const s16x8*)&aT[wr * 32 + 16 + fr][kg * 8];
      s16x8 b0 = *(const s16x8*)&bT[wc * 32 + fr][kg * 8];
      s16x8 b1 = *(const s16x8*)&bT[wc * 32 + 16 + fr][kg * 8];
      acc[0][0] = __builtin_amdgcn_mfma_f32_16x16x32_bf16(a0, b0, acc[0][0], 0, 0, 0);
      acc[0][1] = __builtin_amdgcn_mfma_f32_16x16x32_bf16(a0, b1, acc[0][1], 0, 0, 0);
      acc[1][0] = __builtin_amdgcn_mfma_f32_16x16x32_bf16(a1, b0, acc[1][0], 0, 0, 0);
      acc[1][1] = __builtin_amdgcn_mfma_f32_16x16x32_bf16(a1, b1, acc[1][1], 0, 0, 0);
      __syncthreads();
    }
#pragma unroll
    for (int m = 0; m < 2; ++m)
#pragma unroll
      for (int n = 0; n < 2; ++n)
#pragma unroll
        for (int q = 0; q < 4; ++q) {
          int rl = wr * 32 + m * 16 + kg * 4 + q;
          int cl = wc * 32 + n * 16 + fr;
          float dist = sqrow[rl] + sq[bcol + cl] - 2.0f * acc[m][n][q];
          float sv = ((brow + rl) == (bcol + cl)) ? 0.0f : __expf(-fmaxf(dist, 0.0f));
          simf[rl * 65 + cl] = sv;
        }
    __syncthreads();
    {
      const int c0 = wid * 16;
#pragma unroll
      for (int c = 0; c < 16; ++c) {
        float v = simf[lane * 65 + c0 + c];
        TOPK_INSERT(tv, ti, v, bcol + c0 + c);
      }
    }
    __syncthreads();
  }
#pragma unroll
  for (int s = 0; s < 10; ++s) {
    simf[(lane * 4 + wid) * 20 + s * 2]     = tv[s];
    simf[(lane * 4 + wid) * 20 + s * 2 + 1] = __int_as_float(ti[s]);
  }
  __syncthreads();
  if (t < 64) {
    float mv[10]; int mi[10];
#pragma unroll
    for (int s = 0; s < 10; ++s) { mv[s] = -INFINITY; mi[s] = 0x7fffffff; }
#pragma unroll
    for (int p = 0; p < 4; ++p)
#pragma unroll
      for (int s = 0; s < 10; ++s) {
        float v = simf[(t * 4 + p) * 20 + s * 2];
        int idx = __float_as_int(simf[(t * 4 + p) * 20 + s * 2 + 1]);
        TOPK_INSERT(mv, mi, v, idx);
      }
    float* orow = out + (size_t)(brow + t) * NROWS;
#pragma unroll
    for (int s = 0; s < 10; ++s) orow[mi[s]] = 1.0f;
  }
}

extern "C" void kernel_launch(void* const* d_in, const int* in_sizes, int n_in,
                              void* d_out, int out_size, void* d_ws, size_t ws_size,
                              hipStream_t stream) {
  const float* f = (const float*)d_in[0];
  float* out = (float*)d_out;

  const size_t sq_bytes   = (size_t)NROWS * sizeof(float);          // 49152
  const size_t fbf_bytes  = (size_t)NROWS * DIM * sizeof(unsigned short);
  const size_t part_bytes = (size_t)NROWS * NC * 10 * sizeof(float2);

  float* sq = (float*)d_ws;
  unsigned short* fbf = (unsigned short*)((char*)d_ws + sq_bytes);
  float2* part = (float2*)((char*)d_ws + sq_bytes + fbf_bytes);

  if (ws_size >= sq_bytes + fbf_bytes + part_bytes) {
    prep_kernel<<<NROWS / 4, 256, 0, stream>>>(f, sq, fbf);
    gram_topk<<<dim3(NRB, NC), 256, 0, stream>>>(fbf, sq, part, out);
    merge_scatter<<<NROWS / 128, 256, 0, stream>>>(part, out);
  } else if (ws_size >= sq_bytes + fbf_bytes) {
    prep_kernel<<<NROWS / 4, 256, 0, stream>>>(f, sq, fbf);
    knn_fallback<<<NROWS / 64, 256, 0, stream>>>(fbf, sq, out);
  }
}